// Round 1
// baseline (3074.075 us; speedup 1.0000x reference)
//
#include <hip/hip_runtime.h>

#define N_NODES 50000
#define N_EDGES 800000
#define D_IN 128
#define HIDDEN 128
#define N_CLASSES 40

// ---------------------------------------------------------------------------
// Degree count: one thread per edge, atomic +1.0 into deg[dst]
// ---------------------------------------------------------------------------
__global__ __launch_bounds__(256) void deg_kernel(const int* __restrict__ dst,
                                                  float* __restrict__ deg) {
    int e = blockIdx.x * 256 + threadIdx.x;
    if (e < N_EDGES) atomicAdd(&deg[dst[e]], 1.0f);
}

// ---------------------------------------------------------------------------
// Scatter-add: agg[dst[e]] += feat[src[e]]  (feat is [N,128] fp32)
// One thread per (edge, float4-chunk): 32 chunks/edge, 4 atomics/thread.
// ---------------------------------------------------------------------------
__global__ __launch_bounds__(256) void scatter_kernel(
    const float4* __restrict__ feat4, const int* __restrict__ src,
    const int* __restrict__ dst, float* __restrict__ agg) {
    int idx = blockIdx.x * 256 + threadIdx.x;  // < E*32 = 25.6M, fits int
    if (idx >= N_EDGES * 32) return;
    int e = idx >> 5;
    int c = idx & 31;
    float4 v = feat4[src[e] * 32 + c];
    float* base = agg + dst[e] * 128 + c * 4;
    atomicAdd(base + 0, v.x);
    atomicAdd(base + 1, v.y);
    atomicAdd(base + 2, v.z);
    atomicAdd(base + 3, v.w);
}

// ---------------------------------------------------------------------------
// Layer 1: h[n][j] = relu(b1[j] + (agg[n]/max(deg,1)) . W1l[:,j] + x[n] . W1r[:,j])
// Block = 256 threads, 8 nodes/block. Node rows + 32-row W tiles staged in LDS.
// Thread t: j = t&127, g = t>>7; computes nodes {g, g+2, g+4, g+6} at column j.
// LDS: 8KB rows + 32KB W tiles = 40KB.
// ---------------------------------------------------------------------------
#define L1_NODES 8
__global__ __launch_bounds__(256) void layer1_kernel(
    const float* __restrict__ x, const float* __restrict__ agg,
    const float* __restrict__ deg, const float* __restrict__ W1l,
    const float* __restrict__ W1r, const float* __restrict__ b1,
    float* __restrict__ h) {
    __shared__ float s_a[L1_NODES][128];
    __shared__ float s_x[L1_NODES][128];
    __shared__ float s_wl[32][128];
    __shared__ float s_wr[32][128];

    int n0 = blockIdx.x * L1_NODES;  // 50000/8 = 6250 blocks exactly
    int t = threadIdx.x;

    // Stage the 8 node rows (agg scaled by 1/deg, and x)
    for (int i = t; i < L1_NODES * 128; i += 256) {
        int nl = i >> 7, k = i & 127;
        int n = n0 + nl;
        float inv = 1.0f / fmaxf(deg[n], 1.0f);
        s_a[nl][k] = agg[n * 128 + k] * inv;
        s_x[nl][k] = x[n * 128 + k];
    }

    int j = t & 127;
    int g = t >> 7;  // 0 or 1
    float acc[4];
    float bj = b1[j];
#pragma unroll
    for (int i = 0; i < 4; i++) acc[i] = bj;

    for (int kt = 0; kt < 128; kt += 32) {
        __syncthreads();
        // Stage W tiles [kt:kt+32, :]
        for (int i = t; i < 32 * 128; i += 256) {
            int kk = i >> 7, jj = i & 127;
            s_wl[kk][jj] = W1l[(kt + kk) * 128 + jj];
            s_wr[kk][jj] = W1r[(kt + kk) * 128 + jj];
        }
        __syncthreads();
#pragma unroll 8
        for (int kk = 0; kk < 32; kk++) {
            float wl = s_wl[kk][j];
            float wr = s_wr[kk][j];
#pragma unroll
            for (int i = 0; i < 4; i++) {
                int nl = g + i * 2;
                acc[i] += s_a[nl][kt + kk] * wl + s_x[nl][kt + kk] * wr;
            }
        }
    }

#pragma unroll
    for (int i = 0; i < 4; i++) {
        int nl = g + i * 2;
        h[(n0 + nl) * 128 + j] = fmaxf(acc[i], 0.0f);
    }
}

// ---------------------------------------------------------------------------
// Layer 2: out[n][c] = b2[c] + (agg2[n]/max(deg,1)) . W2l[:,c] + h[n] . W2r[:,c]
// Block = 256 threads, 6 nodes/block (40 threads/node active, 16 idle).
// Node rows staged in LDS; W2 (40KB total) comes from L1/L2.
// ---------------------------------------------------------------------------
#define L2_NODES 6
__global__ __launch_bounds__(256) void layer2_kernel(
    const float* __restrict__ hbuf, const float* __restrict__ agg,
    const float* __restrict__ deg, const float* __restrict__ W2l,
    const float* __restrict__ W2r, const float* __restrict__ b2,
    float* __restrict__ out) {
    __shared__ float s_a[L2_NODES][128];
    __shared__ float s_h[L2_NODES][128];

    int n0 = blockIdx.x * L2_NODES;
    int t = threadIdx.x;

    for (int i = t; i < L2_NODES * 128; i += 256) {
        int nl = i >> 7, k = i & 127;
        int n = n0 + nl;
        if (n < N_NODES) {
            float inv = 1.0f / fmaxf(deg[n], 1.0f);
            s_a[nl][k] = agg[n * 128 + k] * inv;
            s_h[nl][k] = hbuf[n * 128 + k];
        }
    }
    __syncthreads();

    int g = t / 40;
    int c = t % 40;
    if (g < L2_NODES) {
        int n = n0 + g;
        if (n < N_NODES) {
            float acc = b2[c];
#pragma unroll 4
            for (int k = 0; k < 128; k++)
                acc += s_a[g][k] * W2l[k * 40 + c] + s_h[g][k] * W2r[k * 40 + c];
            out[n * 40 + c] = acc;
        }
    }
}

// ---------------------------------------------------------------------------
extern "C" void kernel_launch(void* const* d_in, const int* in_sizes, int n_in,
                              void* d_out, int out_size, void* d_ws, size_t ws_size,
                              hipStream_t stream) {
    const float* x   = (const float*)d_in[0];
    const int*   ei  = (const int*)d_in[1];   // [2, E]: src row then dst row
    const float* W1l = (const float*)d_in[2];
    const float* b1  = (const float*)d_in[3];
    const float* W1r = (const float*)d_in[4];
    const float* W2l = (const float*)d_in[5];
    const float* b2  = (const float*)d_in[6];
    const float* W2r = (const float*)d_in[7];
    float* out = (float*)d_out;

    const int* src = ei;
    const int* dst = ei + N_EDGES;

    // Workspace layout: deg (256KB slot) | agg (25.6MB) | h (25.6MB)
    char* ws = (char*)d_ws;
    const size_t AGG_BYTES = (size_t)N_NODES * 128 * sizeof(float);  // 25.6 MB
    float* deg = (float*)ws;
    float* agg = (float*)(ws + (256 << 10));
    float* h   = (float*)(ws + (256 << 10) + AGG_BYTES);

    hipMemsetAsync(deg, 0, N_NODES * sizeof(float), stream);
    hipMemsetAsync(agg, 0, AGG_BYTES, stream);

    deg_kernel<<<(N_EDGES + 255) / 256, 256, 0, stream>>>(dst, deg);

    // Layer 1 aggregation + GEMM
    scatter_kernel<<<(N_EDGES * 32) / 256, 256, 0, stream>>>(
        (const float4*)x, src, dst, agg);
    layer1_kernel<<<N_NODES / L1_NODES, 256, 0, stream>>>(
        x, agg, deg, W1l, W1r, b1, h);

    // Layer 2 aggregation + GEMM
    hipMemsetAsync(agg, 0, AGG_BYTES, stream);
    scatter_kernel<<<(N_EDGES * 32) / 256, 256, 0, stream>>>(
        (const float4*)h, src, dst, agg);
    layer2_kernel<<<(N_NODES + L2_NODES - 1) / L2_NODES, 256, 0, stream>>>(
        h, agg, deg, W2l, W2r, b2, out);
}

// Round 2
// 632.953 us; speedup vs baseline: 4.8567x; 4.8567x over previous
//
#include <hip/hip_runtime.h>

#define N_NODES 50000
#define N_EDGES 800000
#define D_IN 128
#define HIDDEN 128
#define N_CLASSES 40

// ---------------------------------------------------------------------------
// CSR build step 1: integer in-degree count
// ---------------------------------------------------------------------------
__global__ __launch_bounds__(256) void deg_kernel(const int* __restrict__ dst,
                                                  int* __restrict__ deg) {
    int e = blockIdx.x * 256 + threadIdx.x;
    if (e < N_EDGES) atomicAdd(&deg[dst[e]], 1);
}

// ---------------------------------------------------------------------------
// CSR build step 2: exclusive prefix scan over deg[50000] -> rowstart[50001]
// Single block, 256 threads, chunk = 196 elements/thread, Hillis-Steele on
// the 256 partials in LDS. Also initializes cursor = rowstart copy.
// ---------------------------------------------------------------------------
#define SCAN_CHUNK 196  // 256*196 = 50176 >= 50000
__global__ __launch_bounds__(256) void scan_kernel(const int* __restrict__ deg,
                                                   int* __restrict__ rowstart,
                                                   int* __restrict__ cursor) {
    __shared__ int part[256];
    int t = threadIdx.x;
    int lo = t * SCAN_CHUNK;
    int hi = min(lo + SCAN_CHUNK, N_NODES);
    int s = 0;
    for (int i = lo; i < hi; i++) s += deg[i];
    part[t] = s;
    __syncthreads();
    for (int off = 1; off < 256; off <<= 1) {
        int v = (t >= off) ? part[t - off] : 0;
        __syncthreads();
        part[t] += v;
        __syncthreads();
    }
    int run = (t == 0) ? 0 : part[t - 1];
    for (int i = lo; i < hi; i++) {
        rowstart[i] = run;
        cursor[i] = run;
        run += deg[i];
    }
    if (t == 255) rowstart[N_NODES] = run;  // == N_EDGES
}

// ---------------------------------------------------------------------------
// CSR build step 3: bucket fill. One int atomic per edge.
// ---------------------------------------------------------------------------
__global__ __launch_bounds__(256) void fill_kernel(const int* __restrict__ src,
                                                   const int* __restrict__ dst,
                                                   int* __restrict__ cursor,
                                                   int* __restrict__ csr_src) {
    int e = blockIdx.x * 256 + threadIdx.x;
    if (e < N_EDGES) {
        int p = atomicAdd(&cursor[dst[e]], 1);
        csr_src[p] = src[e];
    }
}

// ---------------------------------------------------------------------------
// Pull-based mean aggregation: agg[n] = (1/max(deg,1)) * sum_{e in CSR[n]} feat[src]
// One wave (64 lanes) per node; lane l holds feat cols [2l, 2l+1] (float2).
// Block = 256 -> 4 nodes/block. 2-edge unroll for ILP on the random gathers.
// Writes agg PRE-SCALED (no deg needed downstream).
// ---------------------------------------------------------------------------
__global__ __launch_bounds__(256) void agg_pull_kernel(
    const float2* __restrict__ feat2, const int* __restrict__ csr_src,
    const int* __restrict__ rowstart, float2* __restrict__ agg2) {
    int n = blockIdx.x * 4 + (threadIdx.x >> 6);
    if (n >= N_NODES) return;
    int l = threadIdx.x & 63;
    int rs = rowstart[n];
    int re = rowstart[n + 1];
    float ax = 0.f, ay = 0.f, bx = 0.f, by = 0.f;
    int e = rs;
    for (; e + 1 < re; e += 2) {
        int s0 = csr_src[e];
        int s1 = csr_src[e + 1];
        float2 v0 = feat2[s0 * 64 + l];
        float2 v1 = feat2[s1 * 64 + l];
        ax += v0.x; ay += v0.y;
        bx += v1.x; by += v1.y;
    }
    if (e < re) {
        int s0 = csr_src[e];
        float2 v0 = feat2[s0 * 64 + l];
        ax += v0.x; ay += v0.y;
    }
    int d = re - rs;
    float inv = 1.0f / (float)max(d, 1);
    float2 r;
    r.x = (ax + bx) * inv;
    r.y = (ay + by) * inv;
    agg2[n * 64 + l] = r;
}

// ---------------------------------------------------------------------------
// Layer 1: h[n][j] = relu(b1[j] + agg[n] . W1l[:,j] + x[n] . W1r[:,j])
// (agg already scaled by 1/deg.) Block = 256 threads, 8 nodes/block.
// ---------------------------------------------------------------------------
#define L1_NODES 8
__global__ __launch_bounds__(256) void layer1_kernel(
    const float* __restrict__ x, const float* __restrict__ agg,
    const float* __restrict__ W1l, const float* __restrict__ W1r,
    const float* __restrict__ b1, float* __restrict__ h) {
    __shared__ float s_a[L1_NODES][128];
    __shared__ float s_x[L1_NODES][128];
    __shared__ float s_wl[32][128];
    __shared__ float s_wr[32][128];

    int n0 = blockIdx.x * L1_NODES;  // 50000/8 = 6250 blocks exactly
    int t = threadIdx.x;

    for (int i = t; i < L1_NODES * 128; i += 256) {
        int nl = i >> 7, k = i & 127;
        int n = n0 + nl;
        s_a[nl][k] = agg[n * 128 + k];
        s_x[nl][k] = x[n * 128 + k];
    }

    int j = t & 127;
    int g = t >> 7;  // 0 or 1
    float acc[4];
    float bj = b1[j];
#pragma unroll
    for (int i = 0; i < 4; i++) acc[i] = bj;

    for (int kt = 0; kt < 128; kt += 32) {
        __syncthreads();
        for (int i = t; i < 32 * 128; i += 256) {
            int kk = i >> 7, jj = i & 127;
            s_wl[kk][jj] = W1l[(kt + kk) * 128 + jj];
            s_wr[kk][jj] = W1r[(kt + kk) * 128 + jj];
        }
        __syncthreads();
#pragma unroll 8
        for (int kk = 0; kk < 32; kk++) {
            float wl = s_wl[kk][j];
            float wr = s_wr[kk][j];
#pragma unroll
            for (int i = 0; i < 4; i++) {
                int nl = g + i * 2;
                acc[i] += s_a[nl][kt + kk] * wl + s_x[nl][kt + kk] * wr;
            }
        }
    }

#pragma unroll
    for (int i = 0; i < 4; i++) {
        int nl = g + i * 2;
        h[(n0 + nl) * 128 + j] = fmaxf(acc[i], 0.0f);
    }
}

// ---------------------------------------------------------------------------
// Layer 2: out[n][c] = b2[c] + agg2[n] . W2l[:,c] + h[n] . W2r[:,c]
// ---------------------------------------------------------------------------
#define L2_NODES 6
__global__ __launch_bounds__(256) void layer2_kernel(
    const float* __restrict__ hbuf, const float* __restrict__ agg,
    const float* __restrict__ W2l, const float* __restrict__ W2r,
    const float* __restrict__ b2, float* __restrict__ out) {
    __shared__ float s_a[L2_NODES][128];
    __shared__ float s_h[L2_NODES][128];

    int n0 = blockIdx.x * L2_NODES;
    int t = threadIdx.x;

    for (int i = t; i < L2_NODES * 128; i += 256) {
        int nl = i >> 7, k = i & 127;
        int n = n0 + nl;
        if (n < N_NODES) {
            s_a[nl][k] = agg[n * 128 + k];
            s_h[nl][k] = hbuf[n * 128 + k];
        }
    }
    __syncthreads();

    int g = t / 40;
    int c = t % 40;
    if (g < L2_NODES) {
        int n = n0 + g;
        if (n < N_NODES) {
            float acc = b2[c];
#pragma unroll 4
            for (int k = 0; k < 128; k++)
                acc += s_a[g][k] * W2l[k * 40 + c] + s_h[g][k] * W2r[k * 40 + c];
            out[n * 40 + c] = acc;
        }
    }
}

// ---------------------------------------------------------------------------
extern "C" void kernel_launch(void* const* d_in, const int* in_sizes, int n_in,
                              void* d_out, int out_size, void* d_ws, size_t ws_size,
                              hipStream_t stream) {
    const float* x   = (const float*)d_in[0];
    const int*   ei  = (const int*)d_in[1];   // [2, E]: src row then dst row
    const float* W1l = (const float*)d_in[2];
    const float* b1  = (const float*)d_in[3];
    const float* W1r = (const float*)d_in[4];
    const float* W2l = (const float*)d_in[5];
    const float* b2  = (const float*)d_in[6];
    const float* W2r = (const float*)d_in[7];
    float* out = (float*)d_out;

    const int* src = ei;
    const int* dst = ei + N_EDGES;

    // Workspace layout (offsets in bytes):
    //   deg      @ 0        (200 KB slot -> 256 KB)
    //   rowstart @ 256 KB   (50001 ints)
    //   cursor   @ 512 KB   (50000 ints)
    //   csr_src  @ 768 KB   (3.2 MB)
    //   agg      @ 4 MB     (25.6 MB)
    //   h        @ 4 MB + 25.6 MB
    char* ws = (char*)d_ws;
    const size_t AGG_BYTES = (size_t)N_NODES * 128 * sizeof(float);
    int* deg      = (int*)(ws);
    int* rowstart = (int*)(ws + (256 << 10));
    int* cursor   = (int*)(ws + (512 << 10));
    int* csr_src  = (int*)(ws + (768 << 10));
    float* agg    = (float*)(ws + (4 << 20));
    float* h      = (float*)(ws + (4 << 20) + AGG_BYTES);

    const int EB = (N_EDGES + 255) / 256;

    // --- CSR build (per call; inputs are restored before every timed launch)
    hipMemsetAsync(deg, 0, N_NODES * sizeof(int), stream);
    deg_kernel<<<EB, 256, 0, stream>>>(dst, deg);
    scan_kernel<<<1, 256, 0, stream>>>(deg, rowstart, cursor);
    fill_kernel<<<EB, 256, 0, stream>>>(src, dst, cursor, csr_src);

    const int AGG_BLOCKS = (N_NODES + 3) / 4;

    // --- Layer 1
    agg_pull_kernel<<<AGG_BLOCKS, 256, 0, stream>>>(
        (const float2*)x, csr_src, rowstart, (float2*)agg);
    layer1_kernel<<<N_NODES / L1_NODES, 256, 0, stream>>>(
        x, agg, W1l, W1r, b1, h);

    // --- Layer 2
    agg_pull_kernel<<<AGG_BLOCKS, 256, 0, stream>>>(
        (const float2*)h, csr_src, rowstart, (float2*)agg);
    layer2_kernel<<<(N_NODES + L2_NODES - 1) / L2_NODES, 256, 0, stream>>>(
        h, agg, W2l, W2r, b2, out);
}

// Round 3
// 504.568 us; speedup vs baseline: 6.0925x; 1.2544x over previous
//
#include <hip/hip_runtime.h>

#define N_NODES 50000
#define N_EDGES 800000
#define D_IN 128
#define HIDDEN 128
#define N_CLASSES 40

// ---------------------------------------------------------------------------
// CSR build step 1: integer in-degree count
// ---------------------------------------------------------------------------
__global__ __launch_bounds__(256) void deg_kernel(const int* __restrict__ dst,
                                                  int* __restrict__ deg) {
    int e = blockIdx.x * 256 + threadIdx.x;
    if (e < N_EDGES) atomicAdd(&deg[dst[e]], 1);
}

// ---------------------------------------------------------------------------
// CSR build step 2: exclusive prefix scan deg[50000] -> rowstart[50001] + cursor
// ---------------------------------------------------------------------------
#define SCAN_CHUNK 196  // 256*196 = 50176 >= 50000
__global__ __launch_bounds__(256) void scan_kernel(const int* __restrict__ deg,
                                                   int* __restrict__ rowstart,
                                                   int* __restrict__ cursor) {
    __shared__ int part[256];
    int t = threadIdx.x;
    int lo = t * SCAN_CHUNK;
    int hi = min(lo + SCAN_CHUNK, N_NODES);
    int s = 0;
    for (int i = lo; i < hi; i++) s += deg[i];
    part[t] = s;
    __syncthreads();
    for (int off = 1; off < 256; off <<= 1) {
        int v = (t >= off) ? part[t - off] : 0;
        __syncthreads();
        part[t] += v;
        __syncthreads();
    }
    int run = (t == 0) ? 0 : part[t - 1];
    for (int i = lo; i < hi; i++) {
        rowstart[i] = run;
        cursor[i] = run;
        run += deg[i];
    }
    if (t == 255) rowstart[N_NODES] = run;
}

// ---------------------------------------------------------------------------
// CSR build step 3: bucket fill. One int atomic per edge.
// ---------------------------------------------------------------------------
__global__ __launch_bounds__(256) void fill_kernel(const int* __restrict__ src,
                                                   const int* __restrict__ dst,
                                                   int* __restrict__ cursor,
                                                   int* __restrict__ csr_src) {
    int e = blockIdx.x * 256 + threadIdx.x;
    if (e < N_EDGES) {
        int p = atomicAdd(&cursor[dst[e]], 1);
        csr_src[p] = src[e];
    }
}

// ---------------------------------------------------------------------------
// Register-blocked fp32 GEMM: C = A[M][128] @ [Wl | Wr]  (each [128][NW])
// Output split: Cl[M][NW], Cr[M][NW]. Block tile BM x BN, thread tile TM x TN,
// 256 threads = (BM/TM)*(BN/TN). K=128, BK=32. A-tile stored transposed in LDS
// (pad +2: conflict-light staging writes, 8B-aligned compute reads).
// ---------------------------------------------------------------------------
template <int BM, int BN, int TM, int TN, int NW>
__global__ __launch_bounds__(256) void gemm_dual(
    const float* __restrict__ A, const float* __restrict__ Wl,
    const float* __restrict__ Wr, float* __restrict__ Cl,
    float* __restrict__ Cr, int M) {
    constexpr int K = 128, BK = 32, PAD = 2;
    __shared__ float sA[BK][BM + PAD];
    __shared__ float sW[BK][BN];

    const int m0 = blockIdx.x * BM;
    const int c0blk = blockIdx.y * BN;
    const int t = threadIdx.x;
    const int tc = t % (BN / TN);
    const int tr = t / (BN / TN);
    const int r0 = tr * TM;
    const int c0 = tc * TN;

    float acc[TM][TN] = {};

    for (int kc = 0; kc < K; kc += BK) {
        if (kc) __syncthreads();
        // Stage A tile (transposed): 8 consecutive lanes read one row's 128B.
        for (int i = t; i < BM * (BK / 4); i += 256) {
            int row = i / (BK / 4);
            int k4 = (i % (BK / 4)) * 4;
            int gr = m0 + row;
            if (gr >= M) gr = M - 1;
            float4 v = *(const float4*)(A + (size_t)gr * K + kc + k4);
            sA[k4 + 0][row] = v.x;
            sA[k4 + 1][row] = v.y;
            sA[k4 + 2][row] = v.z;
            sA[k4 + 3][row] = v.w;
        }
        // Stage W tile (select Wl/Wr per column)
        for (int i = t; i < BK * BN; i += 256) {
            int k = i / BN, c = i % BN;
            int gk = kc + k;
            int gc = c0blk + c;
            sW[k][c] = (gc < NW) ? Wl[gk * NW + gc] : Wr[gk * NW + gc - NW];
        }
        __syncthreads();

#pragma unroll 8
        for (int kk = 0; kk < BK; kk++) {
            float a[TM], w[TN];
#pragma unroll
            for (int i = 0; i < TM; i++) a[i] = sA[kk][r0 + i];
#pragma unroll
            for (int j = 0; j < TN; j++) w[j] = sW[kk][c0 + j];
#pragma unroll
            for (int i = 0; i < TM; i++)
#pragma unroll
                for (int j = 0; j < TN; j++) acc[i][j] += a[i] * w[j];
        }
    }

#pragma unroll
    for (int i = 0; i < TM; i++) {
        int gr = m0 + r0 + i;
        if (gr < M) {
#pragma unroll
            for (int j = 0; j < TN; j++) {
                int gc = c0blk + c0 + j;
                if (gc < NW)
                    Cl[(size_t)gr * NW + gc] = acc[i][j];
                else
                    Cr[(size_t)gr * NW + gc - NW] = acc[i][j];
            }
        }
    }
}

// ---------------------------------------------------------------------------
// Fused aggregation + epilogue for layer 1:
//   h[n] = relu( (1/max(deg,1)) * sum_{s in CSR[n]} yl[s]  + yr[n] + b1 )
// One wave per node, lane l holds float2 cols [2l,2l+1]. h written IN PLACE
// over yr (gathers touch only yl -> no hazard). 4-edge unroll.
// ---------------------------------------------------------------------------
__global__ __launch_bounds__(256) void agg_relu1_kernel(
    const float2* __restrict__ yl2, const int* __restrict__ csr_src,
    const int* __restrict__ rowstart, const float2* __restrict__ b12,
    float2* __restrict__ h2) {
    int n = blockIdx.x * 4 + (threadIdx.x >> 6);
    if (n >= N_NODES) return;
    int l = threadIdx.x & 63;
    int rs = rowstart[n];
    int re = rowstart[n + 1];
    float ax = 0.f, ay = 0.f, bx = 0.f, by = 0.f;
    int e = rs;
    for (; e + 3 < re; e += 4) {
        int s0 = csr_src[e + 0];
        int s1 = csr_src[e + 1];
        int s2 = csr_src[e + 2];
        int s3 = csr_src[e + 3];
        float2 v0 = yl2[(size_t)s0 * 64 + l];
        float2 v1 = yl2[(size_t)s1 * 64 + l];
        float2 v2 = yl2[(size_t)s2 * 64 + l];
        float2 v3 = yl2[(size_t)s3 * 64 + l];
        ax += v0.x; ay += v0.y;
        bx += v1.x; by += v1.y;
        ax += v2.x; ay += v2.y;
        bx += v3.x; by += v3.y;
    }
    for (; e < re; e++) {
        int s0 = csr_src[e];
        float2 v0 = yl2[(size_t)s0 * 64 + l];
        ax += v0.x; ay += v0.y;
    }
    int d = re - rs;
    float inv = 1.0f / (float)max(d, 1);
    float2 r = h2[(size_t)n * 64 + l];  // yr[n] (in-place buffer)
    float2 b = b12[l];
    float2 o;
    o.x = fmaxf((ax + bx) * inv + r.x + b.x, 0.0f);
    o.y = fmaxf((ay + by) * inv + r.y + b.y, 0.0f);
    h2[(size_t)n * 64 + l] = o;
}

// ---------------------------------------------------------------------------
// Fused aggregation + epilogue for layer 2:
//   out[n][c] = (1/max(deg,1)) * sum_{s in CSR[n]} z[s][c] + r[n][c] + b2[c]
// z = h@W2l [N][40], r = h@W2r [N][40]. One wave per node, lanes 0..39 active.
// ---------------------------------------------------------------------------
__global__ __launch_bounds__(256) void agg_out2_kernel(
    const float* __restrict__ z, const float* __restrict__ r,
    const int* __restrict__ csr_src, const int* __restrict__ rowstart,
    const float* __restrict__ b2, float* __restrict__ out) {
    int n = blockIdx.x * 4 + (threadIdx.x >> 6);
    if (n >= N_NODES) return;
    int c = threadIdx.x & 63;
    if (c >= N_CLASSES) return;
    int rs = rowstart[n];
    int re = rowstart[n + 1];
    float a0 = 0.f, a1 = 0.f;
    int e = rs;
    for (; e + 3 < re; e += 4) {
        int s0 = csr_src[e + 0];
        int s1 = csr_src[e + 1];
        int s2 = csr_src[e + 2];
        int s3 = csr_src[e + 3];
        float v0 = z[(size_t)s0 * 40 + c];
        float v1 = z[(size_t)s1 * 40 + c];
        float v2 = z[(size_t)s2 * 40 + c];
        float v3 = z[(size_t)s3 * 40 + c];
        a0 += v0 + v2;
        a1 += v1 + v3;
    }
    for (; e < re; e++) a0 += z[(size_t)csr_src[e] * 40 + c];
    int d = re - rs;
    float inv = 1.0f / (float)max(d, 1);
    out[(size_t)n * 40 + c] = (a0 + a1) * inv + r[(size_t)n * 40 + c] + b2[c];
}

// ---------------------------------------------------------------------------
extern "C" void kernel_launch(void* const* d_in, const int* in_sizes, int n_in,
                              void* d_out, int out_size, void* d_ws, size_t ws_size,
                              hipStream_t stream) {
    const float* x   = (const float*)d_in[0];
    const int*   ei  = (const int*)d_in[1];   // [2, E]: src row then dst row
    const float* W1l = (const float*)d_in[2];
    const float* b1  = (const float*)d_in[3];
    const float* W1r = (const float*)d_in[4];
    const float* W2l = (const float*)d_in[5];
    const float* b2  = (const float*)d_in[6];
    const float* W2r = (const float*)d_in[7];
    float* out = (float*)d_out;

    const int* src = ei;
    const int* dst = ei + N_EDGES;

    // Workspace layout (bytes):
    //   deg      @ 0       | rowstart @ 256K | cursor @ 512K | csr_src @ 768K
    //   yl       @ 4M      (50000*128*4 = 25.6 MB)   [layer-2: zl @ same, zr after]
    //   yr / h   @ 4M+25.6M (25.6 MB, h overwrites yr in place)
    char* ws = (char*)d_ws;
    const size_t F128 = (size_t)N_NODES * 128 * sizeof(float);  // 25.6 MB
    const size_t F40  = (size_t)N_NODES * 40 * sizeof(float);   // 8 MB
    int* deg      = (int*)(ws);
    int* rowstart = (int*)(ws + (256 << 10));
    int* cursor   = (int*)(ws + (512 << 10));
    int* csr_src  = (int*)(ws + (768 << 10));
    float* yl     = (float*)(ws + (4 << 20));
    float* h      = (float*)(ws + (4 << 20) + F128);  // starts life as yr
    float* zl     = yl;                                // reuse yl slot (dead)
    float* zr     = (float*)((char*)yl + F40);

    const int EB = (N_EDGES + 255) / 256;

    // --- CSR build
    hipMemsetAsync(deg, 0, N_NODES * sizeof(int), stream);
    deg_kernel<<<EB, 256, 0, stream>>>(dst, deg);
    scan_kernel<<<1, 256, 0, stream>>>(deg, rowstart, cursor);
    fill_kernel<<<EB, 256, 0, stream>>>(src, dst, cursor, csr_src);

    const int AGG_BLOCKS = (N_NODES + 3) / 4;

    // --- Layer 1: y = x @ [W1l | W1r]; h = relu(mean(yl) + yr + b1)
    {
        dim3 grid((N_NODES + 127) / 128, 2);
        gemm_dual<128, 128, 8, 8, 128><<<grid, 256, 0, stream>>>(
            x, W1l, W1r, yl, h /*yr*/, N_NODES);
    }
    agg_relu1_kernel<<<AGG_BLOCKS, 256, 0, stream>>>(
        (const float2*)yl, csr_src, rowstart, (const float2*)b1, (float2*)h);

    // --- Layer 2: z = h @ [W2l | W2r]; out = mean(zl) + zr + b2
    {
        dim3 grid((N_NODES + 63) / 64, 1);
        gemm_dual<64, 80, 4, 5, 40><<<grid, 256, 0, stream>>>(
            h, W2l, W2r, zl, zr, N_NODES);
    }
    agg_out2_kernel<<<AGG_BLOCKS, 256, 0, stream>>>(
        zl, zr, csr_src, rowstart, b2, out);
}

// Round 4
// 386.561 us; speedup vs baseline: 7.9524x; 1.3053x over previous
//
#include <hip/hip_runtime.h>

#define N_NODES 50000
#define N_EDGES 800000
#define D_IN 128
#define HIDDEN 128
#define N_CLASSES 40

#define SCAN_BLOCKS 196  // 196*256 = 50176 >= 50000

// ---------------------------------------------------------------------------
// CSR build step 1: integer in-degree count
// ---------------------------------------------------------------------------
__global__ __launch_bounds__(256) void deg_kernel(const int* __restrict__ dst,
                                                  int* __restrict__ deg) {
    int e = blockIdx.x * 256 + threadIdx.x;
    if (e < N_EDGES) atomicAdd(&deg[dst[e]], 1);
}

// ---------------------------------------------------------------------------
// CSR build step 2a: per-block partial sums of deg (256 nodes/block)
// ---------------------------------------------------------------------------
__global__ __launch_bounds__(256) void partial_kernel(
    const int* __restrict__ deg, int* __restrict__ block_sums) {
    __shared__ int red[256];
    int t = threadIdx.x;
    int n = blockIdx.x * 256 + t;
    red[t] = (n < N_NODES) ? deg[n] : 0;
    __syncthreads();
    for (int off = 128; off > 0; off >>= 1) {
        if (t < off) red[t] += red[t + off];
        __syncthreads();
    }
    if (t == 0) block_sums[blockIdx.x] = red[0];
}

// ---------------------------------------------------------------------------
// CSR build step 2b: single-block exclusive scan of block_sums[SCAN_BLOCKS]
// ---------------------------------------------------------------------------
__global__ __launch_bounds__(256) void scan_sums_kernel(
    int* __restrict__ block_sums) {
    __shared__ int part[256];
    int t = threadIdx.x;
    part[t] = (t < SCAN_BLOCKS) ? block_sums[t] : 0;
    __syncthreads();
    for (int off = 1; off < 256; off <<= 1) {
        int v = (t >= off) ? part[t - off] : 0;
        __syncthreads();
        part[t] += v;
        __syncthreads();
    }
    // exclusive: block b gets sum of blocks [0, b)
    if (t < SCAN_BLOCKS) block_sums[t] = (t == 0) ? 0 : part[t - 1];
}

// ---------------------------------------------------------------------------
// CSR build step 2c: block-local exclusive scan + global offset ->
// rowstart[n], cursor[n]. rowstart[N_NODES] = N_EDGES (constant).
// ---------------------------------------------------------------------------
__global__ __launch_bounds__(256) void write_offsets_kernel(
    const int* __restrict__ deg, const int* __restrict__ block_sums,
    int* __restrict__ rowstart, int* __restrict__ cursor) {
    __shared__ int part[256];
    int t = threadIdx.x;
    int n = blockIdx.x * 256 + t;
    int d = (n < N_NODES) ? deg[n] : 0;
    part[t] = d;
    __syncthreads();
    for (int off = 1; off < 256; off <<= 1) {
        int v = (t >= off) ? part[t - off] : 0;
        __syncthreads();
        part[t] += v;
        __syncthreads();
    }
    if (n < N_NODES) {
        int excl = part[t] - d + block_sums[blockIdx.x];
        rowstart[n] = excl;
        cursor[n] = excl;
    }
    if (blockIdx.x == 0 && t == 0) rowstart[N_NODES] = N_EDGES;
}

// ---------------------------------------------------------------------------
// CSR build step 3: bucket fill. One int atomic per edge.
// ---------------------------------------------------------------------------
__global__ __launch_bounds__(256) void fill_kernel(const int* __restrict__ src,
                                                   const int* __restrict__ dst,
                                                   int* __restrict__ cursor,
                                                   int* __restrict__ csr_src) {
    int e = blockIdx.x * 256 + threadIdx.x;
    if (e < N_EDGES) {
        int p = atomicAdd(&cursor[dst[e]], 1);
        csr_src[p] = src[e];
    }
}

// ---------------------------------------------------------------------------
// Register-blocked fp32 GEMM: C = A[M][128] @ [Wl | Wr]  (each [128][NW])
// Output split: Cl[M][NW], Cr[M][NW]. Block tile BM x BN, thread tile TM x TN,
// 256 threads = (BM/TM)*(BN/TN). K=128, BK=32. A-tile stored transposed in LDS.
// ---------------------------------------------------------------------------
template <int BM, int BN, int TM, int TN, int NW>
__global__ __launch_bounds__(256) void gemm_dual(
    const float* __restrict__ A, const float* __restrict__ Wl,
    const float* __restrict__ Wr, float* __restrict__ Cl,
    float* __restrict__ Cr, int M) {
    constexpr int K = 128, BK = 32, PAD = 2;
    __shared__ float sA[BK][BM + PAD];
    __shared__ float sW[BK][BN];

    const int m0 = blockIdx.x * BM;
    const int c0blk = blockIdx.y * BN;
    const int t = threadIdx.x;
    const int tc = t % (BN / TN);
    const int tr = t / (BN / TN);
    const int r0 = tr * TM;
    const int c0 = tc * TN;

    float acc[TM][TN] = {};

    for (int kc = 0; kc < K; kc += BK) {
        if (kc) __syncthreads();
        for (int i = t; i < BM * (BK / 4); i += 256) {
            int row = i / (BK / 4);
            int k4 = (i % (BK / 4)) * 4;
            int gr = m0 + row;
            if (gr >= M) gr = M - 1;
            float4 v = *(const float4*)(A + (size_t)gr * K + kc + k4);
            sA[k4 + 0][row] = v.x;
            sA[k4 + 1][row] = v.y;
            sA[k4 + 2][row] = v.z;
            sA[k4 + 3][row] = v.w;
        }
        for (int i = t; i < BK * BN; i += 256) {
            int k = i / BN, c = i % BN;
            int gk = kc + k;
            int gc = c0blk + c;
            sW[k][c] = (gc < NW) ? Wl[gk * NW + gc] : Wr[gk * NW + gc - NW];
        }
        __syncthreads();

#pragma unroll 8
        for (int kk = 0; kk < BK; kk++) {
            float a[TM], w[TN];
#pragma unroll
            for (int i = 0; i < TM; i++) a[i] = sA[kk][r0 + i];
#pragma unroll
            for (int j = 0; j < TN; j++) w[j] = sW[kk][c0 + j];
#pragma unroll
            for (int i = 0; i < TM; i++)
#pragma unroll
                for (int j = 0; j < TN; j++) acc[i][j] += a[i] * w[j];
        }
    }

#pragma unroll
    for (int i = 0; i < TM; i++) {
        int gr = m0 + r0 + i;
        if (gr < M) {
#pragma unroll
            for (int j = 0; j < TN; j++) {
                int gc = c0blk + c0 + j;
                if (gc < NW)
                    Cl[(size_t)gr * NW + gc] = acc[i][j];
                else
                    Cr[(size_t)gr * NW + gc - NW] = acc[i][j];
            }
        }
    }
}

// ---------------------------------------------------------------------------
// Fused aggregation + epilogue for layer 1:
//   h[n] = relu( (1/max(deg,1)) * sum_{s in CSR[n]} yl[s]  + yr[n] + b1 )
// One wave per node, lane l holds float2 cols [2l,2l+1]. h written IN PLACE
// over yr (gathers touch only yl -> no hazard). 4-edge unroll.
// ---------------------------------------------------------------------------
__global__ __launch_bounds__(256) void agg_relu1_kernel(
    const float2* __restrict__ yl2, const int* __restrict__ csr_src,
    const int* __restrict__ rowstart, const float2* __restrict__ b12,
    float2* __restrict__ h2) {
    int n = blockIdx.x * 4 + (threadIdx.x >> 6);
    if (n >= N_NODES) return;
    int l = threadIdx.x & 63;
    int rs = rowstart[n];
    int re = rowstart[n + 1];
    float ax = 0.f, ay = 0.f, bx = 0.f, by = 0.f;
    int e = rs;
    for (; e + 3 < re; e += 4) {
        int s0 = csr_src[e + 0];
        int s1 = csr_src[e + 1];
        int s2 = csr_src[e + 2];
        int s3 = csr_src[e + 3];
        float2 v0 = yl2[(size_t)s0 * 64 + l];
        float2 v1 = yl2[(size_t)s1 * 64 + l];
        float2 v2 = yl2[(size_t)s2 * 64 + l];
        float2 v3 = yl2[(size_t)s3 * 64 + l];
        ax += v0.x; ay += v0.y;
        bx += v1.x; by += v1.y;
        ax += v2.x; ay += v2.y;
        bx += v3.x; by += v3.y;
    }
    for (; e < re; e++) {
        int s0 = csr_src[e];
        float2 v0 = yl2[(size_t)s0 * 64 + l];
        ax += v0.x; ay += v0.y;
    }
    int d = re - rs;
    float inv = 1.0f / (float)max(d, 1);
    float2 r = h2[(size_t)n * 64 + l];  // yr[n] (in-place buffer)
    float2 b = b12[l];
    float2 o;
    o.x = fmaxf((ax + bx) * inv + r.x + b.x, 0.0f);
    o.y = fmaxf((ay + by) * inv + r.y + b.y, 0.0f);
    h2[(size_t)n * 64 + l] = o;
}

// ---------------------------------------------------------------------------
// Fused aggregation + epilogue for layer 2:
//   out[n][c] = (1/max(deg,1)) * sum_{s in CSR[n]} z[s][c] + r[n][c] + b2[c]
// ---------------------------------------------------------------------------
__global__ __launch_bounds__(256) void agg_out2_kernel(
    const float* __restrict__ z, const float* __restrict__ r,
    const int* __restrict__ csr_src, const int* __restrict__ rowstart,
    const float* __restrict__ b2, float* __restrict__ out) {
    int n = blockIdx.x * 4 + (threadIdx.x >> 6);
    if (n >= N_NODES) return;
    int c = threadIdx.x & 63;
    if (c >= N_CLASSES) return;
    int rs = rowstart[n];
    int re = rowstart[n + 1];
    float a0 = 0.f, a1 = 0.f;
    int e = rs;
    for (; e + 3 < re; e += 4) {
        int s0 = csr_src[e + 0];
        int s1 = csr_src[e + 1];
        int s2 = csr_src[e + 2];
        int s3 = csr_src[e + 3];
        float v0 = z[(size_t)s0 * 40 + c];
        float v1 = z[(size_t)s1 * 40 + c];
        float v2 = z[(size_t)s2 * 40 + c];
        float v3 = z[(size_t)s3 * 40 + c];
        a0 += v0 + v2;
        a1 += v1 + v3;
    }
    for (; e < re; e++) a0 += z[(size_t)csr_src[e] * 40 + c];
    int d = re - rs;
    float inv = 1.0f / (float)max(d, 1);
    out[(size_t)n * 40 + c] = (a0 + a1) * inv + r[(size_t)n * 40 + c] + b2[c];
}

// ---------------------------------------------------------------------------
extern "C" void kernel_launch(void* const* d_in, const int* in_sizes, int n_in,
                              void* d_out, int out_size, void* d_ws, size_t ws_size,
                              hipStream_t stream) {
    const float* x   = (const float*)d_in[0];
    const int*   ei  = (const int*)d_in[1];   // [2, E]: src row then dst row
    const float* W1l = (const float*)d_in[2];
    const float* b1  = (const float*)d_in[3];
    const float* W1r = (const float*)d_in[4];
    const float* W2l = (const float*)d_in[5];
    const float* b2  = (const float*)d_in[6];
    const float* W2r = (const float*)d_in[7];
    float* out = (float*)d_out;

    const int* src = ei;
    const int* dst = ei + N_EDGES;

    // Workspace layout (bytes):
    //   deg @ 0 | rowstart @ 256K | cursor @ 512K | block_sums @ 760K
    //   csr_src @ 768K | yl @ 4M (25.6MB) | yr/h @ 4M+25.6M
    char* ws = (char*)d_ws;
    const size_t F128 = (size_t)N_NODES * 128 * sizeof(float);  // 25.6 MB
    const size_t F40  = (size_t)N_NODES * 40 * sizeof(float);   // 8 MB
    int* deg        = (int*)(ws);
    int* rowstart   = (int*)(ws + (256 << 10));
    int* cursor     = (int*)(ws + (512 << 10));
    int* block_sums = (int*)(ws + (760 << 10));
    int* csr_src    = (int*)(ws + (768 << 10));
    float* yl       = (float*)(ws + (4 << 20));
    float* h        = (float*)(ws + (4 << 20) + F128);  // starts life as yr
    float* zl       = yl;                                // reuse yl slot
    float* zr       = (float*)((char*)yl + F40);

    const int EB = (N_EDGES + 255) / 256;

    // --- CSR build (parallel scan)
    hipMemsetAsync(deg, 0, N_NODES * sizeof(int), stream);
    deg_kernel<<<EB, 256, 0, stream>>>(dst, deg);
    partial_kernel<<<SCAN_BLOCKS, 256, 0, stream>>>(deg, block_sums);
    scan_sums_kernel<<<1, 256, 0, stream>>>(block_sums);
    write_offsets_kernel<<<SCAN_BLOCKS, 256, 0, stream>>>(deg, block_sums,
                                                          rowstart, cursor);
    fill_kernel<<<EB, 256, 0, stream>>>(src, dst, cursor, csr_src);

    const int AGG_BLOCKS = (N_NODES + 3) / 4;

    // --- Layer 1: y = x @ [W1l | W1r]; h = relu(mean(yl) + yr + b1)
    {
        dim3 grid((N_NODES + 127) / 128, 2);
        gemm_dual<128, 128, 8, 8, 128><<<grid, 256, 0, stream>>>(
            x, W1l, W1r, yl, h /*yr*/, N_NODES);
    }
    agg_relu1_kernel<<<AGG_BLOCKS, 256, 0, stream>>>(
        (const float2*)yl, csr_src, rowstart, (const float2*)b1, (float2*)h);

    // --- Layer 2: z = h @ [W2l | W2r]; out = mean(zl) + zr + b2
    {
        dim3 grid((N_NODES + 63) / 64, 1);
        gemm_dual<64, 80, 4, 5, 40><<<grid, 256, 0, stream>>>(
            h, W2l, W2r, zl, zr, N_NODES);
    }
    agg_out2_kernel<<<AGG_BLOCKS, 256, 0, stream>>>(
        zl, zr, csr_src, rowstart, b2, out);
}

// Round 6
// 291.795 us; speedup vs baseline: 10.5350x; 1.3248x over previous
//
#include <hip/hip_runtime.h>

#define N_NODES 50000
#define N_EDGES 800000
#define D_IN 128
#define HIDDEN 128
#define N_CLASSES 40

#define SCAN_BLOCKS 196  // 196*256 = 50176 >= 50000
#define M_PAD 50048      // 782 * 64

typedef __attribute__((ext_vector_type(8))) short short8;
typedef __attribute__((ext_vector_type(4))) float floatx4;

static __device__ __forceinline__ unsigned short f2bf(float f) {
    unsigned u = __float_as_uint(f);
    u = (u + 0x7fffu + ((u >> 16) & 1u)) >> 16;  // RNE
    return (unsigned short)u;
}
static __device__ __forceinline__ float bf2f(unsigned short b) {
    return __uint_as_float(((unsigned)b) << 16);
}

// ---------------------------------------------------------------------------
// CSR build
// ---------------------------------------------------------------------------
__global__ __launch_bounds__(256) void deg_kernel(const int* __restrict__ dst,
                                                  int* __restrict__ deg) {
    int e = blockIdx.x * 256 + threadIdx.x;
    if (e < N_EDGES) atomicAdd(&deg[dst[e]], 1);
}

__global__ __launch_bounds__(256) void partial_kernel(
    const int* __restrict__ deg, int* __restrict__ block_sums) {
    __shared__ int red[256];
    int t = threadIdx.x;
    int n = blockIdx.x * 256 + t;
    red[t] = (n < N_NODES) ? deg[n] : 0;
    __syncthreads();
    for (int off = 128; off > 0; off >>= 1) {
        if (t < off) red[t] += red[t + off];
        __syncthreads();
    }
    if (t == 0) block_sums[blockIdx.x] = red[0];
}

__global__ __launch_bounds__(256) void scan_sums_kernel(
    int* __restrict__ block_sums) {
    __shared__ int part[256];
    int t = threadIdx.x;
    part[t] = (t < SCAN_BLOCKS) ? block_sums[t] : 0;
    __syncthreads();
    for (int off = 1; off < 256; off <<= 1) {
        int v = (t >= off) ? part[t - off] : 0;
        __syncthreads();
        part[t] += v;
        __syncthreads();
    }
    if (t < SCAN_BLOCKS) block_sums[t] = (t == 0) ? 0 : part[t - 1];
}

__global__ __launch_bounds__(256) void write_offsets_kernel(
    const int* __restrict__ deg, const int* __restrict__ block_sums,
    int* __restrict__ rowstart, int* __restrict__ cursor) {
    __shared__ int part[256];
    int t = threadIdx.x;
    int n = blockIdx.x * 256 + t;
    int d = (n < N_NODES) ? deg[n] : 0;
    part[t] = d;
    __syncthreads();
    for (int off = 1; off < 256; off <<= 1) {
        int v = (t >= off) ? part[t - off] : 0;
        __syncthreads();
        part[t] += v;
        __syncthreads();
    }
    if (n < N_NODES) {
        int excl = part[t] - d + block_sums[blockIdx.x];
        rowstart[n] = excl;
        cursor[n] = excl;
    }
    if (blockIdx.x == 0 && t == 0) rowstart[N_NODES] = N_EDGES;
}

__global__ __launch_bounds__(256) void fill_kernel(const int* __restrict__ src,
                                                   const int* __restrict__ dst,
                                                   int* __restrict__ cursor,
                                                   int* __restrict__ csr_src) {
    int e = blockIdx.x * 256 + threadIdx.x;
    if (e < N_EDGES) {
        int p = atomicAdd(&cursor[dst[e]], 1);
        csr_src[p] = src[e];
    }
}

// ---------------------------------------------------------------------------
// Convert x [50000][128] fp32 -> xb bf16 (row-major). 8 elems/thread.
// ---------------------------------------------------------------------------
__global__ __launch_bounds__(256) void convert_x_kernel(
    const float4* __restrict__ xin, uint4* __restrict__ xb) {
    int i = blockIdx.x * 256 + threadIdx.x;
    if (i >= (N_NODES * 128) / 8) return;
    float4 v0 = xin[2 * i];
    float4 v1 = xin[2 * i + 1];
    uint4 o;
    o.x = (unsigned)f2bf(v0.x) | ((unsigned)f2bf(v0.y) << 16);
    o.y = (unsigned)f2bf(v0.z) | ((unsigned)f2bf(v0.w) << 16);
    o.z = (unsigned)f2bf(v1.x) | ((unsigned)f2bf(v1.y) << 16);
    o.w = (unsigned)f2bf(v1.z) | ((unsigned)f2bf(v1.w) << 16);
    xb[i] = o;
}

// ---------------------------------------------------------------------------
// Transpose+convert weights: Wt1[n][k] = W1{l,r}[k][n-split]  (256x128 bf16)
//                            Wt2[n][k] = W2{l,r}[k][n-split]  (80x128 bf16)
// ---------------------------------------------------------------------------
__global__ __launch_bounds__(256) void convert_w1_kernel(
    const float* __restrict__ Wl, const float* __restrict__ Wr,
    unsigned short* __restrict__ Wt) {
    int t = blockIdx.x * 256 + threadIdx.x;
    if (t >= 256 * 128) return;
    int n = t >> 7, k = t & 127;
    float v = (n < 128) ? Wl[k * 128 + n] : Wr[k * 128 + (n - 128)];
    Wt[n * 128 + k] = f2bf(v);
}

__global__ __launch_bounds__(256) void convert_w2_kernel(
    const float* __restrict__ Wl, const float* __restrict__ Wr,
    unsigned short* __restrict__ Wt) {
    int t = blockIdx.x * 256 + threadIdx.x;
    if (t >= 80 * 128) return;
    int n = t >> 7, k = t & 127;
    float v = (n < 40) ? Wl[k * 40 + n] : Wr[k * 40 + (n - 40)];
    Wt[n * 128 + k] = f2bf(v);
}

// ---------------------------------------------------------------------------
// MFMA GEMM layer 1: [xb 50048x128 bf16] @ [Wt 256x128 bf16 (pre-T)] ->
//   cols 0..127 -> ylb (bf16), cols 128..255 -> yr (fp32).
// Block = 4 waves; wave w covers rows m0..m0+63, cols w*64..w*64+63
// (4x4 frags of 16x16x32). Frags loaded straight from global (L2-hot).
// Layouts (m89/m120-verified): A[m=lane&15][k=quad*8+j],
// B[k=quad*8+j][n=lane&15], D col=lane&15, row=quad*4+reg.
// ---------------------------------------------------------------------------
__global__ __launch_bounds__(256) void gemm1_mfma_kernel(
    const unsigned short* __restrict__ xb, const unsigned short* __restrict__ Wt,
    unsigned short* __restrict__ ylb, float* __restrict__ yr) {
    const int wave = threadIdx.x >> 6;
    const int lane = threadIdx.x & 63;
    const int r = lane & 15, q = lane >> 4;
    const int m0 = blockIdx.x * 64;
    const int n0 = wave * 64;

    floatx4 acc[4][4];
#pragma unroll
    for (int i = 0; i < 4; i++)
#pragma unroll
        for (int j = 0; j < 4; j++) acc[i][j] = (floatx4){0.f, 0.f, 0.f, 0.f};

#pragma unroll
    for (int kc = 0; kc < 128; kc += 32) {
        short8 a[4], b[4];
#pragma unroll
        for (int mi = 0; mi < 4; mi++)
            a[mi] = *(const short8*)(xb + (size_t)(m0 + mi * 16 + r) * 128 + kc + q * 8);
#pragma unroll
        for (int ni = 0; ni < 4; ni++)
            b[ni] = *(const short8*)(Wt + (size_t)(n0 + ni * 16 + r) * 128 + kc + q * 8);
#pragma unroll
        for (int mi = 0; mi < 4; mi++)
#pragma unroll
            for (int ni = 0; ni < 4; ni++)
                acc[mi][ni] = __builtin_amdgcn_mfma_f32_16x16x32_bf16(
                    a[mi], b[ni], acc[mi][ni], 0, 0, 0);
    }

#pragma unroll
    for (int mi = 0; mi < 4; mi++) {
        int rowb = m0 + mi * 16 + q * 4;
#pragma unroll
        for (int ni = 0; ni < 4; ni++) {
            int col = n0 + ni * 16 + r;
#pragma unroll
            for (int reg = 0; reg < 4; reg++) {
                int gr = rowb + reg;
                if (gr < N_NODES) {
                    float v = acc[mi][ni][reg];
                    if (col < 128)
                        ylb[(size_t)gr * 128 + col] = f2bf(v);
                    else
                        yr[(size_t)gr * 128 + (col - 128)] = v;
                }
            }
        }
    }
}

// ---------------------------------------------------------------------------
// MFMA GEMM layer 2: [hb 50048x128 bf16] @ [Wt2 80x128 bf16] ->
//   cols 0..39 -> zl fp32, cols 40..79 -> zr fp32.
// Block = 4 waves; wave w covers rows m0+w*16 .. +15, all 80 cols (5 frags).
// ---------------------------------------------------------------------------
__global__ __launch_bounds__(256) void gemm2_mfma_kernel(
    const unsigned short* __restrict__ hb, const unsigned short* __restrict__ Wt,
    float* __restrict__ zl, float* __restrict__ zr) {
    const int wave = threadIdx.x >> 6;
    const int lane = threadIdx.x & 63;
    const int r = lane & 15, q = lane >> 4;
    const int m0 = blockIdx.x * 64 + wave * 16;

    floatx4 acc[5];
#pragma unroll
    for (int i = 0; i < 5; i++) acc[i] = (floatx4){0.f, 0.f, 0.f, 0.f};

#pragma unroll
    for (int kc = 0; kc < 128; kc += 32) {
        short8 a = *(const short8*)(hb + (size_t)(m0 + r) * 128 + kc + q * 8);
        short8 b[5];
#pragma unroll
        for (int ni = 0; ni < 5; ni++)
            b[ni] = *(const short8*)(Wt + (size_t)(ni * 16 + r) * 128 + kc + q * 8);
#pragma unroll
        for (int ni = 0; ni < 5; ni++)
            acc[ni] = __builtin_amdgcn_mfma_f32_16x16x32_bf16(a, b[ni], acc[ni], 0, 0, 0);
    }

    int rowb = m0 + q * 4;
#pragma unroll
    for (int ni = 0; ni < 5; ni++) {
        int col = ni * 16 + r;
#pragma unroll
        for (int reg = 0; reg < 4; reg++) {
            int gr = rowb + reg;
            if (gr < N_NODES) {
                float v = acc[ni][reg];
                if (col < 40)
                    zl[(size_t)gr * 40 + col] = v;
                else
                    zr[(size_t)gr * 40 + (col - 40)] = v;
            }
        }
    }
}

// ---------------------------------------------------------------------------
// Fused agg + epilogue layer 1 (bf16 in / bf16 out):
//   h[n] = relu( mean_{s in CSR[n]} yl[s] + yr[n] + b1 ), packed 2xbf16/lane.
// ---------------------------------------------------------------------------
__global__ __launch_bounds__(256) void agg_relu1_kernel(
    const unsigned int* __restrict__ ylu, const int* __restrict__ csr_src,
    const int* __restrict__ rowstart, const float2* __restrict__ b12,
    const float2* __restrict__ yr2, unsigned int* __restrict__ hbu) {
    int n = blockIdx.x * 4 + (threadIdx.x >> 6);
    if (n >= N_NODES) return;
    int l = threadIdx.x & 63;
    int rs = rowstart[n];
    int re = rowstart[n + 1];
    float ax = 0.f, ay = 0.f, bx = 0.f, by = 0.f;
    int e = rs;
    for (; e + 3 < re; e += 4) {
        int s0 = csr_src[e + 0];
        int s1 = csr_src[e + 1];
        int s2 = csr_src[e + 2];
        int s3 = csr_src[e + 3];
        unsigned u0 = ylu[(size_t)s0 * 64 + l];
        unsigned u1 = ylu[(size_t)s1 * 64 + l];
        unsigned u2 = ylu[(size_t)s2 * 64 + l];
        unsigned u3 = ylu[(size_t)s3 * 64 + l];
        ax += bf2f(u0 & 0xffff); ay += bf2f(u0 >> 16);
        bx += bf2f(u1 & 0xffff); by += bf2f(u1 >> 16);
        ax += bf2f(u2 & 0xffff); ay += bf2f(u2 >> 16);
        bx += bf2f(u3 & 0xffff); by += bf2f(u3 >> 16);
    }
    for (; e < re; e++) {
        unsigned u0 = ylu[(size_t)csr_src[e] * 64 + l];
        ax += bf2f(u0 & 0xffff); ay += bf2f(u0 >> 16);
    }
    int d = re - rs;
    float inv = 1.0f / (float)max(d, 1);
    float2 rr = yr2[(size_t)n * 64 + l];
    float2 b = b12[l];
    float ox = fmaxf((ax + bx) * inv + rr.x + b.x, 0.0f);
    float oy = fmaxf((ay + by) * inv + rr.y + b.y, 0.0f);
    hbu[(size_t)n * 64 + l] = (unsigned)f2bf(ox) | ((unsigned)f2bf(oy) << 16);
}

// ---------------------------------------------------------------------------
// Fused agg + epilogue layer 2 (fp32): out = mean(zl) + zr + b2
// ---------------------------------------------------------------------------
__global__ __launch_bounds__(256) void agg_out2_kernel(
    const float* __restrict__ z, const float* __restrict__ r,
    const int* __restrict__ csr_src, const int* __restrict__ rowstart,
    const float* __restrict__ b2, float* __restrict__ out) {
    int n = blockIdx.x * 4 + (threadIdx.x >> 6);
    if (n >= N_NODES) return;
    int c = threadIdx.x & 63;
    if (c >= N_CLASSES) return;
    int rs = rowstart[n];
    int re = rowstart[n + 1];
    float a0 = 0.f, a1 = 0.f;
    int e = rs;
    for (; e + 3 < re; e += 4) {
        int s0 = csr_src[e + 0];
        int s1 = csr_src[e + 1];
        int s2 = csr_src[e + 2];
        int s3 = csr_src[e + 3];
        float v0 = z[(size_t)s0 * 40 + c];
        float v1 = z[(size_t)s1 * 40 + c];
        float v2 = z[(size_t)s2 * 40 + c];
        float v3 = z[(size_t)s3 * 40 + c];
        a0 += v0 + v2;
        a1 += v1 + v3;
    }
    for (; e < re; e++) a0 += z[(size_t)csr_src[e] * 40 + c];
    int d = re - rs;
    float inv = 1.0f / (float)max(d, 1);
    out[(size_t)n * 40 + c] = (a0 + a1) * inv + r[(size_t)n * 40 + c] + b2[c];
}

// ---------------------------------------------------------------------------
extern "C" void kernel_launch(void* const* d_in, const int* in_sizes, int n_in,
                              void* d_out, int out_size, void* d_ws, size_t ws_size,
                              hipStream_t stream) {
    const float* x   = (const float*)d_in[0];
    const int*   ei  = (const int*)d_in[1];   // [2, E]: src row then dst row
    const float* W1l = (const float*)d_in[2];
    const float* b1  = (const float*)d_in[3];
    const float* W1r = (const float*)d_in[4];
    const float* W2l = (const float*)d_in[5];
    const float* b2  = (const float*)d_in[6];
    const float* W2r = (const float*)d_in[7];
    float* out = (float*)d_out;

    const int* src = ei;
    const int* dst = ei + N_EDGES;

    // Workspace layout (bytes) — NO OVERLAPS (round-5 bug: Wt2 sat inside
    // csr_src's [786,432 , 3,986,432) span and got clobbered/clobbered it):
    //  deg@0 | rowstart@256K | cursor@512K | block_sums@760K
    //  csr_src @ 768K           ends 3,986,432
    //  Wt1     @ 3,987,456      (65,536)  ends 4,052,992
    //  Wt2     @ 4,052,992      (20,480)  ends 4,073,472   (< 4 MiB)
    //  xb/hb   @ 4 MiB          (50048*128*2 = 12,812,288) ends 17,006,592
    //  ylb     @ 17,006,592     (12,800,000)               ends 29,806,592
    //  yr      @ 29,806,592     (25,600,000)               ends 55,406,592
    //  zl      @ 30,408,704 (8MB), zr @ 38,408,704 (8MB) — inside dead yr
    char* ws = (char*)d_ws;
    int* deg        = (int*)(ws);
    int* rowstart   = (int*)(ws + (256 << 10));
    int* cursor     = (int*)(ws + (512 << 10));
    int* block_sums = (int*)(ws + (760 << 10));
    int* csr_src    = (int*)(ws + (768 << 10));
    unsigned short* Wt1 = (unsigned short*)(ws + 3987456);
    unsigned short* Wt2 = (unsigned short*)(ws + 4052992);
    unsigned short* xb  = (unsigned short*)(ws + (4 << 20));
    unsigned short* hb  = (unsigned short*)(ws + (4 << 20));  // overlays xb
    unsigned short* ylb = (unsigned short*)(ws + 17006592);
    float* yr           = (float*)(ws + 29806592);
    float* zl           = (float*)(ws + 30408704);  // inside dead yr
    float* zr           = (float*)(ws + 38408704);

    const int EB = (N_EDGES + 255) / 256;

    // --- CSR build (parallel scan)
    hipMemsetAsync(deg, 0, N_NODES * sizeof(int), stream);
    deg_kernel<<<EB, 256, 0, stream>>>(dst, deg);
    partial_kernel<<<SCAN_BLOCKS, 256, 0, stream>>>(deg, block_sums);
    scan_sums_kernel<<<1, 256, 0, stream>>>(block_sums);
    write_offsets_kernel<<<SCAN_BLOCKS, 256, 0, stream>>>(deg, block_sums,
                                                          rowstart, cursor);
    fill_kernel<<<EB, 256, 0, stream>>>(src, dst, cursor, csr_src);

    // --- Precision conversions
    convert_x_kernel<<<(N_NODES * 128 / 8 + 255) / 256, 256, 0, stream>>>(
        (const float4*)x, (uint4*)xb);
    convert_w1_kernel<<<(256 * 128 + 255) / 256, 256, 0, stream>>>(W1l, W1r, Wt1);
    convert_w2_kernel<<<(80 * 128 + 255) / 256, 256, 0, stream>>>(W2l, W2r, Wt2);

    const int AGG_BLOCKS = (N_NODES + 3) / 4;
    const int GEMM_BLOCKS = M_PAD / 64;  // 782

    // --- Layer 1
    gemm1_mfma_kernel<<<GEMM_BLOCKS, 256, 0, stream>>>(xb, Wt1, ylb, yr);
    agg_relu1_kernel<<<AGG_BLOCKS, 256, 0, stream>>>(
        (const unsigned int*)ylb, csr_src, rowstart, (const float2*)b1,
        (const float2*)yr, (unsigned int*)hb);

    // --- Layer 2
    gemm2_mfma_kernel<<<GEMM_BLOCKS, 256, 0, stream>>>(hb, Wt2, zl, zr);
    agg_out2_kernel<<<AGG_BLOCKS, 256, 0, stream>>>(
        zl, zr, csr_src, rowstart, b2, out);
}